// Round 12
// baseline (1397.704 us; speedup 1.0000x reference)
//
#include <hip/hip_runtime.h>
#include <cstddef>

#define CONF_THR 0.2f
#define IOU_THR  0.5f
#define IMG_SZ   448.0f

typedef __attribute__((ext_vector_type(8))) _Float16 half8;  // 8 f16 (4 VGPRs)
typedef __attribute__((ext_vector_type(4))) float f32x4;
typedef unsigned short u16;
typedef unsigned int   u32;

__device__ __forceinline__ u16 f2h(float x) {
    _Float16 h = (_Float16)x;
    return __builtin_bit_cast(u16, h);
}
__device__ __forceinline__ float h2f(u16 b) {
    _Float16 h = __builtin_bit_cast(_Float16, b);
    return (float)h;
}

// global -> LDS direct (16B per lane; LDS dest = wave-uniform base + lane*16)
#define GLOAD_LDS16(gsrc, ldst)                                              \
    __builtin_amdgcn_global_load_lds(                                        \
        (const __attribute__((address_space(1))) void*)(gsrc),               \
        (__attribute__((address_space(3))) void*)(ldst), 16, 0, 0)

// ---------------------------------------------------------------------------
// features (NCHW fp32) -> 2 fp16 limb planes of (x * 16), NHWC zero-PADDED
// ---------------------------------------------------------------------------
__global__ __launch_bounds__(256)
void pad_split(const float* __restrict__ x, u16* __restrict__ xp,
               const int Cin, const int H, const int W,
               const int PW, const int PHW, const long PS)
{
    __shared__ float lds[64][200];
    const int t  = threadIdx.x;
    const int b  = blockIdx.x >> 5;
    const int cc = blockIdx.x & 31;
    const int ci0 = cc * 64;
    const int HW = H * W;

    for (int r = 0; r < 64; ++r) {
        for (int i = t; i < HW; i += 256)
            lds[r][i] = x[((long)b * Cin + ci0 + r) * HW + i];
    }
    __syncthreads();

    const int lci = t & 63;
    const int lp  = t >> 6;
    for (int pp = 0; pp < PHW / 4; ++pp) {
        const int pix = pp * 4 + lp;
        const int py = pix / PW, px = pix % PW;
        float v = 0.f;
        if (py >= 1 && py <= H && px >= 1 && px <= W)
            v = lds[lci][(py - 1) * W + (px - 1)];
        v *= 16.0f;                               // activation scale
        u16 h = f2h(v);
        u16 m = f2h(v - h2f(h));
        const long off = ((long)b * PHW + pix) * Cin + ci0 + lci;
        xp[off] = h; xp[PS + off] = m;
    }
}

// ---------------------------------------------------------------------------
// Conv-weight split to tap-major fp16 limbs of (w * 256). Per-layer launch
// into ONE reused wT buffer right before its conv (r9: warm-wT matters).
// ---------------------------------------------------------------------------
__global__ __launch_bounds__(256)
void wsplit_kernel(const float* __restrict__ w, u16* __restrict__ wT, int Cin)
{
    __shared__ float ws_l[2304];
    const int t  = threadIdx.x;
    const int cb = blockIdx.x;
    const int co = blockIdx.y;
    const long base = ((long)co * Cin + cb * 256) * 9;
    for (int i = t; i < 2304; i += 256) ws_l[i] = w[base + i];
    __syncthreads();
    const int ci = cb * 256 + t;
    const long PS = (long)9 * 1024 * Cin;
    #pragma unroll
    for (int tap = 0; tap < 9; ++tap) {
        float v = ws_l[t * 9 + tap] * 256.0f;     // weight scale
        u16 h = f2h(v);
        u16 m = f2h(v - h2f(h));
        long off = ((long)tap * 1024 + co) * Cin + ci;
        wT[off] = h; wT[PS + off] = m;
    }
}

// ---------------------------------------------------------------------------
// MFMA conv v3 = r10's proven 256m x 128n x 64ci tile + DISTANCE-2 prefetch.
// LDS double-buffered (96KB -> 1 block/CU). Per step:
//   compute(cur) -> __syncthreads -> stage(s+2 into cur)
// so the barrier's vmcnt(0) drain waits on loads issued ONE FULL compute
// phase (~1200cyc) earlier (they've landed), not just-issued ones (r11 bug:
// distance-1 + drain-0 = full latency exposed every step, MfmaUtil 29%).
// No inline asm, no race surface: buf writes vs reads always separated by a
// full barrier+drain. z deepened for 1-block/CU grid quantization.
// VGPR ~60-70 -> (512,4) safe (r6 spill lesson: never cap below acc size).
// ---------------------------------------------------------------------------
template<int STRIDE>
__global__ __launch_bounds__(512, 4)
void conv_mfma(const u16* __restrict__ xp, const u16* __restrict__ wT,
               float* __restrict__ partial,
               const int Cin, const int PW, const int PHW,
               const int Wout, const int Ntot,
               const int sppsh, const int steps_pb, const int Npad,
               const long PSx)
{
    __shared__ u16 Alds[2][256 * 64];   // 2 x 32KB
    __shared__ u16 Blds[2][128 * 64];   // 2 x 16KB

    const int t  = threadIdx.x;

    // ---- T1 XCD swizzle (grids 800/504, both %8==0; neutral but free) ----
    const int gx = gridDim.x, gy = gridDim.y;
    const int nwg = gx * gy * gridDim.z;
    const int bid = blockIdx.x + gx * (blockIdx.y + gy * blockIdx.z);
    const int cpx = nwg >> 3;
    const int swz = (bid & 7) * cpx + (bid >> 3);
    const int bx  = swz % gx;
    const int rem = swz / gx;
    const int by  = rem % gy;
    const int bz  = rem / gy;

    const int m0 = bx * 256;
    const int n0 = by * 128;
    const int g0 = bz * steps_pb;
    const int HWout = Wout * Wout;

    // ---- B source precompute ----
    int bpix[2], bblk[2];
    #pragma unroll
    for (int c = 0; c < 2; ++c) {
        const int idx = c * 512 + t;
        const int col = idx >> 3;
        const int blk = idx & 7;
        int n = n0 + col; if (n >= Ntot) n = 0;
        const int b  = n / HWout;
        const int rp = n - b * HWout;
        const int oy = rp / Wout;
        const int ox = rp - oy * Wout;
        bpix[c] = b * PHW + oy * STRIDE * PW + ox * STRIDE;
        bblk[c] = (blk ^ (col & 7)) * 8;
    }
    // ---- A source precompute ----
    const int arow = t >> 3;
    const int ablk = ((t & 7) ^ (arow & 7)) * 8;
    const int wbase = (t & 448) * 16;

    const int wid = t >> 6, l = t & 63;
    const int wm = wid >> 1, wn = wid & 1;
    const int l16 = l & 15, lhi = l >> 4;

    const f32x4 zero4 = {0.f, 0.f, 0.f, 0.f};
    f32x4 acc[4][4];
    #pragma unroll
    for (int i = 0; i < 4; ++i)
        #pragma unroll
        for (int j = 0; j < 4; ++j) acc[i][j] = zero4;

    auto decode_stage = [&](int g, int buf) {
        const int phase = g >> sppsh;
        const int cs    = g - (phase << sppsh);
        const int pair  = phase / 9;                 // 0,1,2
        const int tap   = phase - pair * 9;
        const int pA = (0x100 >> (pair * 4)) & 15;   // h,h,m
        const int pB = (0x010 >> (pair * 4)) & 15;   // h,m,h
        const int ci0 = cs * 64;
        const int tapoff = (tap / 3) * PW + (tap % 3);
        const u16* Ag = wT + ((long)(pA * 9 + tap) * 1024 + m0) * Cin + ci0 + ablk;
        #pragma unroll
        for (int c = 0; c < 4; ++c)
            GLOAD_LDS16(Ag + (long)(c * 64 + arow) * Cin,
                        (char*)Alds[buf] + c * 8192 + wbase);
        const u16* Bg = xp + (long)pB * PSx + (long)tapoff * Cin + ci0;
        #pragma unroll
        for (int c = 0; c < 2; ++c)
            GLOAD_LDS16(Bg + (long)bpix[c] * Cin + bblk[c],
                        (char*)Blds[buf] + c * 8192 + wbase);
    };

    // prologue: fill both buffers (one cold drain at the barrier)
    decode_stage(g0, 0);
    if (steps_pb > 1) decode_stage(g0 + 1, 1);
    __syncthreads();

    for (int s = 0; s < steps_pb; ++s) {
        const int cur = s & 1;

        #pragma unroll
        for (int j = 0; j < 2; ++j) {
            const int kb = j * 64 + lhi * 16;
            half8 af[4], bf[4];
            #pragma unroll
            for (int f = 0; f < 4; ++f) {
                const int row = wm * 64 + f * 16 + l16;
                af[f] = *(const half8*)((const char*)Alds[cur] + row * 128
                                        + (kb ^ ((row & 7) << 4)));
            }
            #pragma unroll
            for (int f = 0; f < 4; ++f) {
                const int cc = wn * 64 + f * 16 + l16;
                bf[f] = *(const half8*)((const char*)Blds[cur] + cc * 128
                                        + (kb ^ ((cc & 7) << 4)));
            }
            #pragma unroll
            for (int fm = 0; fm < 4; ++fm)
                #pragma unroll
                for (int fn = 0; fn < 4; ++fn)
                    acc[fm][fn] = __builtin_amdgcn_mfma_f32_16x16x32_f16(
                        af[fm], bf[fn], acc[fm][fn], 0, 0, 0);
        }

        __syncthreads();   // ends reads of cur; drains step-(s+1) loads
                           // (issued one full compute phase ago)
        if (s + 2 < steps_pb)
            decode_stage(g0 + s + 2, cur);   // refill cur for step s+2
    }

    // fp32 partials: partial[z][1024][Npad]
    const long pbase = (long)bz * 1024;
    #pragma unroll
    for (int fm = 0; fm < 4; ++fm) {
        #pragma unroll
        for (int r = 0; r < 4; ++r) {
            const long mrow = pbase + m0 + wm * 64 + fm * 16 + lhi * 4 + r;
            float* prow = partial + mrow * Npad + n0 + wn * 64 + l16;
            #pragma unroll
            for (int fn = 0; fn < 4; ++fn)
                prow[fn * 16] = acc[fm][fn][r];
        }
    }
}

// ---------------------------------------------------------------------------
// Sum K-chunk partials, /4096 + bias + leakyReLU -> padded NHWC fp16 2-plane.
// ---------------------------------------------------------------------------
__global__ __launch_bounds__(256)
void reduce_nhwc(const float* __restrict__ partial, const float* __restrict__ bias,
                 u16* __restrict__ yp,
                 const int S, const int Npad, const int Ntot,
                 const int Wout, const int PW, const int PHW, const long PSy)
{
    __shared__ float lds[64][65];
    const int t  = threadIdx.x;
    const int m0 = blockIdx.x * 64;
    const int n0 = blockIdx.y * 64;
    const int HWout = Wout * Wout;

    const int lm = t >> 6, ln = t & 63;
    for (int r = 0; r < 16; ++r) {
        const int m = r * 4 + lm;
        const int n = n0 + ln;
        float v = 0.f;
        if (n < Ntot) {
            for (int s = 0; s < S; ++s)
                v += partial[((long)s * 1024 + m0 + m) * Npad + n];
            v = v * (1.0f / 4096.0f) + bias[m0 + m];
            v = (v >= 0.f) ? v : 0.1f * v;
        }
        lds[m][ln] = v;
    }
    __syncthreads();

    const int wn_ = t >> 6, wci = t & 63;
    for (int r = 0; r < 16; ++r) {
        const int pr = r * 4 + wn_;
        const int nn = n0 + pr;
        if (nn < Ntot) {
            const int b = nn / HWout;
            const int p = nn - b * HWout;
            const int py = p / Wout + 1, px = p % Wout + 1;
            const long off = ((long)b * PHW + py * PW + px) * 1024 + m0 + wci;
            const float vs = lds[wci][pr] * 16.0f;   // activation scale
            u16 h = f2h(vs);
            u16 m = f2h(vs - h2f(h));
            yp[off] = h; yp[PSy + off] = m;
        }
    }
}

// ---------------------------------------------------------------------------
// conv4 epilogue: partials -> fp32 NCHW (feeds fc1)
// ---------------------------------------------------------------------------
__global__ __launch_bounds__(256)
void reduce_f32(const float* __restrict__ partial, const float* __restrict__ bias,
                float* __restrict__ yf,
                const int S, const int Npad, const int Ntot, const int HWout)
{
    const long idx = (long)blockIdx.x * 256 + threadIdx.x;
    if (idx >= (long)1024 * Ntot) return;
    const int m = (int)(idx / Ntot);
    const int n = (int)(idx - (long)m * Ntot);
    float v = 0.f;
    for (int s = 0; s < S; ++s)
        v += partial[((long)s * 1024 + m) * Npad + n];
    v = v * (1.0f / 4096.0f) + bias[m];
    v = (v >= 0.f) ? v : 0.1f * v;
    const int b = n / HWout, pix = n - b * HWout;
    yf[((long)b * 1024 + m) * HWout + pix] = v;
}

// ---------------------------------------------------------------------------
// fc1: out(16,4096) = x(16,50176) @ W(50176,4096); 98 K-chunks of 512.
// ---------------------------------------------------------------------------
__global__ __launch_bounds__(256)
void fc1_partial(const float* __restrict__ x, const float* __restrict__ w,
                 float* __restrict__ part)
{
    __shared__ float xs[512][16];   // 32KB
    const int tid = threadIdx.x;
    const int n   = blockIdx.x * 1024 + tid * 4;
    const int kc  = blockIdx.y;
    const int k0  = kc * 512;

    for (int i = tid; i < 512 * 16; i += 256) {
        const int j = i >> 4;
        const int b = i & 15;
        xs[j][b] = x[(size_t)b * 50176 + k0 + j];
    }
    __syncthreads();

    f32x4 acc[16];
    #pragma unroll
    for (int b = 0; b < 16; ++b) acc[b] = (f32x4){0.f, 0.f, 0.f, 0.f};

    for (int j = 0; j < 512; ++j) {
        const f32x4 wv = *(const f32x4*)&w[(size_t)(k0 + j) * 4096 + n];
        #pragma unroll
        for (int b = 0; b < 16; ++b) {
            const float xb = xs[j][b];
            #pragma unroll
            for (int c = 0; c < 4; ++c)
                acc[b][c] = fmaf(xb, wv[c], acc[b][c]);
        }
    }

    #pragma unroll
    for (int b = 0; b < 16; ++b)
        *(f32x4*)&part[((size_t)kc * 16 + b) * 4096 + n] = acc[b];
}

__global__ __launch_bounds__(256)
void fc1_reduce(const float* __restrict__ part, const float* __restrict__ bias,
                float* __restrict__ y)
{
    const int i = blockIdx.x * 256 + threadIdx.x;
    float s = 0.f;
    for (int kc = 0; kc < 98; ++kc) s += part[(size_t)kc * 65536 + i];
    s += bias[i & 4095];
    y[i] = (s >= 0.f) ? s : 0.1f * s;
}

// ---------------------------------------------------------------------------
// fc2: out(16,1470) = x(16,4096) @ W(4096,1470); K split into 32 chunks.
// ---------------------------------------------------------------------------
__global__ __launch_bounds__(256)
void fc2_partial(const float* __restrict__ x, const float* __restrict__ w,
                 float* __restrict__ part)
{
    __shared__ float xs[128][16];
    const int tid = threadIdx.x;
    const int n   = blockIdx.x * 256 + tid;
    const int kc  = blockIdx.y;
    const int k0  = kc * 128;

    for (int i = tid; i < 128 * 16; i += 256) {
        const int j = i >> 4;
        const int b = i & 15;
        xs[j][b] = x[(size_t)b * 4096 + k0 + j];
    }
    __syncthreads();

    float acc[16] = {};
    if (n < 1470) {
        for (int j = 0; j < 128; ++j) {
            const float wv = w[(size_t)(k0 + j) * 1470 + n];
            #pragma unroll
            for (int b4 = 0; b4 < 4; ++b4) {
                const float4 xv = *(const float4*)&xs[j][b4 * 4];
                acc[b4*4+0] = fmaf(xv.x, wv, acc[b4*4+0]);
                acc[b4*4+1] = fmaf(xv.y, wv, acc[b4*4+1]);
                acc[b4*4+2] = fmaf(xv.z, wv, acc[b4*4+2]);
                acc[b4*4+3] = fmaf(xv.w, wv, acc[b4*4+3]);
            }
        }
        #pragma unroll
        for (int b = 0; b < 16; ++b)
            part[((size_t)kc * 16 + b) * 1470 + n] = acc[b];
    }
}

__global__ __launch_bounds__(256)
void fc2_reduce(const float* __restrict__ part, const float* __restrict__ bias,
                float* __restrict__ y)
{
    const int i = blockIdx.x * 256 + threadIdx.x;
    if (i >= 16 * 1470) return;
    float s = 0.f;
    for (int kc = 0; kc < 32; ++kc) s += part[(size_t)kc * 23520 + i];
    const int n = i % 1470;
    s += bias[n];
    y[i] = 1.0f / (1.0f + expf(-s));
}

// ---------------------------------------------------------------------------
// Decode + per-batch NMS (mirrors JAX semantics incl. stable argsort)
// ---------------------------------------------------------------------------
__global__ __launch_bounds__(128)
void decode_nms(const float* __restrict__ out2, float* __restrict__ dout)
{
    const int b = blockIdx.x;
    const int t = threadIdx.x;
    const float cell = 1.0f / 7.0f;
    const float* o = out2 + (size_t)b * 1470;

    __shared__ float bx[98][4];
    __shared__ float sc[98];
    __shared__ float area[98];
    __shared__ int   order[98];
    __shared__ int   rankof[98];
    __shared__ int   supp[98];
    __shared__ int   keep_s[98];

    if (t < 98) {
        const int gA = t / 14;
        const int r  = t % 14;
        const int gB = r >> 1;
        const int nb = r & 1;
        const int base = gB * 210 + gA * 30 + nb * 5;
        const float v0 = o[base + 0];
        const float v1 = o[base + 1];
        const float w  = o[base + 2];
        const float h  = o[base + 3];
        const float s  = o[base + 4];
        const float cx = v0 * cell + (float)gA * cell;
        const float cy = v1 * cell + (float)gB * cell;
        const float x1 = cx - 0.5f * w;
        const float y1 = cy - 0.5f * h;
        const float x2 = cx + 0.5f * w;
        const float y2 = cy + 0.5f * h;
        bx[t][0] = x1; bx[t][1] = y1; bx[t][2] = x2; bx[t][3] = y2;
        sc[t] = s;
        area[t] = (x2 - x1) * (y2 - y1);
        supp[t] = 0;
        keep_s[t] = 0;
    }
    __syncthreads();

    if (t < 98) {
        const float si = (sc[t] >= CONF_THR) ? sc[t] : -1.0f;
        int rank = 0;
        for (int j = 0; j < 98; ++j) {
            const float sj = (sc[j] >= CONF_THR) ? sc[j] : -1.0f;
            rank += (sj > si) || (sj == si && j < t);
        }
        order[rank] = t;
        rankof[t] = rank;
    }
    __syncthreads();

    for (int i = 0; i < 98; ++i) {
        const int oi = order[i];
        const bool ki = (sc[oi] >= CONF_THR) && (supp[i] == 0);
        if (t == 0) keep_s[i] = ki ? 1 : 0;
        if (ki && t < 98 && t > i) {
            const int oj = order[t];
            const float xx1 = fmaxf(bx[oi][0], bx[oj][0]);
            const float yy1 = fmaxf(bx[oi][1], bx[oj][1]);
            const float xx2 = fminf(bx[oi][2], bx[oj][2]);
            const float yy2 = fminf(bx[oi][3], bx[oj][3]);
            const float iw = fmaxf(xx2 - xx1, 0.f);
            const float ih = fmaxf(yy2 - yy1, 0.f);
            const float inter = iw * ih;
            const float iou = inter / (area[oi] + area[oj] - inter);
            if (iou > IOU_THR) supp[t] = 1;
        }
        __syncthreads();
    }

    float* out_boxes  = dout;
    float* out_scores = dout + 6272;
    float* out_keep   = dout + 7840;
    float* out_labels = dout + 9408;

    if (t < 98) {
        const bool kp = keep_s[rankof[t]] != 0;
        const size_t bi = ((size_t)b * 98 + t) * 4;
        out_boxes[bi + 0] = kp ? bx[t][0] * IMG_SZ : 0.f;
        out_boxes[bi + 1] = kp ? bx[t][1] * IMG_SZ : 0.f;
        out_boxes[bi + 2] = kp ? bx[t][2] * IMG_SZ : 0.f;
        out_boxes[bi + 3] = kp ? bx[t][3] * IMG_SZ : 0.f;
        out_scores[(size_t)b * 98 + t] = kp ? sc[t] : 0.f;
        out_keep[(size_t)b * 98 + t]   = kp ? 1.f : 0.f;
    }
    for (int i = t; i < 49 * 20; i += 128) {
        const int g  = i / 20;
        const int c  = i - g * 20;
        const int gA = g / 7;
        const int gB = g - gA * 7;
        out_labels[(size_t)b * 980 + i] = o[gB * 210 + gA * 30 + 10 + c];
    }
}

// ---------------------------------------------------------------------------
extern "C" void kernel_launch(void* const* d_in, const int* in_sizes, int n_in,
                              void* d_out, int out_size, void* d_ws, size_t ws_size,
                              hipStream_t stream)
{
    (void)in_sizes; (void)n_in; (void)out_size; (void)ws_size;

    const float* features = (const float*)d_in[0];
    const float* w1 = (const float*)d_in[1];
    const float* b1 = (const float*)d_in[2];
    const float* w2 = (const float*)d_in[3];
    const float* b2 = (const float*)d_in[4];
    const float* w3 = (const float*)d_in[5];
    const float* b3 = (const float*)d_in[6];
    const float* w4 = (const float*)d_in[7];
    const float* b4 = (const float*)d_in[8];
    const float* fc1_w = (const float*)d_in[9];
    const float* fc1_b = (const float*)d_in[10];
    const float* fc2_w = (const float*)d_in[11];
    const float* fc2_b = (const float*)d_in[12];

    // ---- workspace plan (~240 MB, r10 warm-wT layout; partial grown for z=8/18) ----
    char* W = (char*)d_ws;
    size_t o = 0;
    auto alloc = [&](size_t bytes) -> char* {
        char* r = W + o; o += (bytes + 255) & ~(size_t)255; return r;
    };
    u16*   wT      = (u16*)  alloc(75497472ULL);  // 2*9*1024*2048*2 (per-layer reuse)
    u16*   xp      = (u16*)  alloc(33554432ULL);  // features: 2*16*256*2048*2
    u16*   actA    = (u16*)  alloc(16777216ULL);  // conv1 out: 2*16*256*1024*2
    float* a4      = (float*)alloc(3211264ULL);   // conv4 out fp32 NCHW
    float* partial = (float*)alloc(104857600ULL); // max(8*1024*3200, 18*1024*896)*4
    float* fc1o    = (float*)alloc(262144ULL);
    float* part2   = (float*)alloc(3010560ULL);
    float* fc2o    = (float*)alloc(94080ULL);
    (void)alloc(4096);
    // aliases inside xp (dead after conv1's conv_mfma):
    float* part1 = (float*)xp;                    // 25.7MB (=98*65536*4), live fc1 only
    u16*   actB  = (u16*)(xp + (24u << 20) / 2);  // 5.3MB @ xp+24MB, conv2..conv4

    const long PSxp = 8388608L;   // 16*256*2048
    const long PSa  = 4194304L;   // 16*256*1024
    const long PSb  = 1327104L;   // 16*81*1024

    // features -> padded NHWC 2-plane (x16)
    pad_split<<<512, 256, 0, stream>>>(features, xp, 2048, 14, 14, 16, 256, PSxp);

    // conv1: Cin=2048; 27 phases * 32 cs = 864 K-steps, z=8 -> 108/block
    // grid (4,25,8) = 800 blocks (96KB LDS -> 1 block/CU; 3.125 fill rounds)
    wsplit_kernel<<<dim3(8, 1024), 256, 0, stream>>>(w1, wT, 2048);
    hipMemsetAsync(actA, 0, 16777216ULL, stream);
    conv_mfma<1><<<dim3(4, 25, 8), 512, 0, stream>>>(
        xp, wT, partial, 2048, 16, 256, 14, 3136, 5, 108, 3200, PSxp);
    hipMemsetAsync(actB, 0, 5308416ULL, stream);       // xp dead; zero pads
    reduce_nhwc<<<dim3(16, 49), 256, 0, stream>>>(partial, b1, actA,
                                                  8, 3200, 3136, 14, 16, 256, PSa);

    // conv2: Cin=1024, stride 2; 27 phases * 16 cs = 432 K-steps, z=18 -> 24/block
    // grid (4,7,18) = 504 blocks (1.97 fill rounds)
    wsplit_kernel<<<dim3(4, 1024), 256, 0, stream>>>(w2, wT, 1024);
    conv_mfma<2><<<dim3(4, 7, 18), 512, 0, stream>>>(
        actA, wT, partial, 1024, 16, 256, 7, 784, 4, 24, 896, PSa);
    reduce_nhwc<<<dim3(16, 13), 256, 0, stream>>>(partial, b2, actB,
                                                  18, 896, 784, 7, 9, 81, PSb);

    // conv3: 7x7, padded 9x9
    wsplit_kernel<<<dim3(4, 1024), 256, 0, stream>>>(w3, wT, 1024);
    conv_mfma<1><<<dim3(4, 7, 18), 512, 0, stream>>>(
        actB, wT, partial, 1024, 9, 81, 7, 784, 4, 24, 896, PSb);
    reduce_nhwc<<<dim3(16, 13), 256, 0, stream>>>(partial, b3, actB,
                                                  18, 896, 784, 7, 9, 81, PSb);

    // conv4 -> fp32 NCHW a4
    wsplit_kernel<<<dim3(4, 1024), 256, 0, stream>>>(w4, wT, 1024);
    conv_mfma<1><<<dim3(4, 7, 18), 512, 0, stream>>>(
        actB, wT, partial, 1024, 9, 81, 7, 784, 4, 24, 896, PSb);
    reduce_f32<<<3136, 256, 0, stream>>>(partial, b4, a4, 18, 896, 784, 49);

    // fc1 (float4 loads, 98-way K-split) / fc2 / decode
    fc1_partial<<<dim3(4, 98), 256, 0, stream>>>(a4, fc1_w, part1);
    fc1_reduce<<<256, 256, 0, stream>>>(part1, fc1_b, fc1o);

    fc2_partial<<<dim3(6, 32), 256, 0, stream>>>(fc1o, fc2_w, part2);
    fc2_reduce<<<92, 256, 0, stream>>>(part2, fc2_b, fc2o);

    decode_nms<<<16, 128, 0, stream>>>(fc2o, (float*)d_out);
}

// Round 13
// 1058.896 us; speedup vs baseline: 1.3200x; 1.3200x over previous
//
#include <hip/hip_runtime.h>
#include <cstddef>

#define CONF_THR 0.2f
#define IOU_THR  0.5f
#define IMG_SZ   448.0f

typedef __attribute__((ext_vector_type(8))) _Float16 half8;  // 8 f16 (4 VGPRs)
typedef __attribute__((ext_vector_type(4))) float f32x4;
typedef unsigned short u16;
typedef unsigned int   u32;

__device__ __forceinline__ u16 f2h(float x) {
    _Float16 h = (_Float16)x;
    return __builtin_bit_cast(u16, h);
}
__device__ __forceinline__ float h2f(u16 b) {
    _Float16 h = __builtin_bit_cast(_Float16, b);
    return (float)h;
}

// global -> LDS direct (16B per lane; LDS dest = wave-uniform base + lane*16)
#define GLOAD_LDS16(gsrc, ldst)                                              \
    __builtin_amdgcn_global_load_lds(                                        \
        (const __attribute__((address_space(1))) void*)(gsrc),               \
        (__attribute__((address_space(3))) void*)(ldst), 16, 0, 0)

// ---------------------------------------------------------------------------
// features (NCHW fp32) -> 2 fp16 limb planes of (x * 16), NHWC zero-PADDED
// ---------------------------------------------------------------------------
__global__ __launch_bounds__(256)
void pad_split(const float* __restrict__ x, u16* __restrict__ xp,
               const int Cin, const int H, const int W,
               const int PW, const int PHW, const long PS)
{
    __shared__ float lds[64][200];
    const int t  = threadIdx.x;
    const int b  = blockIdx.x >> 5;
    const int cc = blockIdx.x & 31;
    const int ci0 = cc * 64;
    const int HW = H * W;

    for (int r = 0; r < 64; ++r) {
        for (int i = t; i < HW; i += 256)
            lds[r][i] = x[((long)b * Cin + ci0 + r) * HW + i];
    }
    __syncthreads();

    const int lci = t & 63;
    const int lp  = t >> 6;
    for (int pp = 0; pp < PHW / 4; ++pp) {
        const int pix = pp * 4 + lp;
        const int py = pix / PW, px = pix % PW;
        float v = 0.f;
        if (py >= 1 && py <= H && px >= 1 && px <= W)
            v = lds[lci][(py - 1) * W + (px - 1)];
        v *= 16.0f;                               // activation scale
        u16 h = f2h(v);
        u16 m = f2h(v - h2f(h));
        const long off = ((long)b * PHW + pix) * Cin + ci0 + lci;
        xp[off] = h; xp[PS + off] = m;
    }
}

// ---------------------------------------------------------------------------
// Conv-weight split to tap-major fp16 limbs of (w * 256). Per-layer launch
// into ONE reused wT buffer right before its conv (r9: warm-wT matters;
// fused cold-buffer variant cost +120us).
// ---------------------------------------------------------------------------
__global__ __launch_bounds__(256)
void wsplit_kernel(const float* __restrict__ w, u16* __restrict__ wT, int Cin)
{
    __shared__ float ws_l[2304];
    const int t  = threadIdx.x;
    const int cb = blockIdx.x;
    const int co = blockIdx.y;
    const long base = ((long)co * Cin + cb * 256) * 9;
    for (int i = t; i < 2304; i += 256) ws_l[i] = w[base + i];
    __syncthreads();
    const int ci = cb * 256 + t;
    const long PS = (long)9 * 1024 * Cin;
    #pragma unroll
    for (int tap = 0; tap < 9; ++tap) {
        float v = ws_l[t * 9 + tap] * 256.0f;     // weight scale
        u16 h = f2h(v);
        u16 m = f2h(v - h2f(h));
        long off = ((long)tap * 1024 + co) * Cin + ci;
        wT[off] = h; wT[PS + off] = m;
    }
}

// ---------------------------------------------------------------------------
// MFMA conv, r10-proven structure (the bank: 1088us total, MfmaUtil 41%,
// ~910 TF = this 2-barrier structure's measured ceiling).
// Tile 256m x 128n x 64ci, 512 thr (8 waves). A,B single-buffered LDS (48KB,
// 1.5-2 blocks/CU -> m114 inter-block overlap hides the barrier drain).
// fp16 2-limb x 3 pairs (hh,hm,mh) = exact-fp32-grade error (~2^-24 rel).
// FAILED alternatives (keep for the record): r6 (512,6) -> acc spill, 7.5GB
// scratch traffic; r11 256^2-dbuf distance-1 -> drain-0 exposes latency,
// MfmaUtil 29%; r12 distance-2 96KB dbuf -> 1 block/CU kills overlap, 27%.
// Escaping this ceiling needs the full counted-vmcnt 8-phase template.
// ---------------------------------------------------------------------------
template<int STRIDE>
__global__ __launch_bounds__(512, 4)
void conv_mfma(const u16* __restrict__ xp, const u16* __restrict__ wT,
               float* __restrict__ partial,
               const int Cin, const int PW, const int PHW,
               const int Wout, const int Ntot,
               const int sppsh, const int steps_pb, const int Npad,
               const long PSx)
{
    __shared__ u16 Alds[256 * 64];   // 32KB
    __shared__ u16 Blds[128 * 64];   // 16KB

    const int t  = threadIdx.x;

    // ---- T1 XCD swizzle (neutral r9 but free; grids %8==0) ----
    const int gx = gridDim.x, gy = gridDim.y;
    const int nwg = gx * gy * gridDim.z;
    const int bid = blockIdx.x + gx * (blockIdx.y + gy * blockIdx.z);
    const int cpx = nwg >> 3;
    const int swz = (bid & 7) * cpx + (bid >> 3);
    const int bx  = swz % gx;
    const int rem = swz / gx;
    const int by  = rem % gy;
    const int bz  = rem / gy;

    const int m0 = bx * 256;
    const int n0 = by * 128;
    const int g0 = bz * steps_pb;
    const int HWout = Wout * Wout;

    // ---- B source precompute ----
    int bpix[2], bblk[2];
    #pragma unroll
    for (int c = 0; c < 2; ++c) {
        const int idx = c * 512 + t;
        const int col = idx >> 3;
        const int blk = idx & 7;
        int n = n0 + col; if (n >= Ntot) n = 0;
        const int b  = n / HWout;
        const int rp = n - b * HWout;
        const int oy = rp / Wout;
        const int ox = rp - oy * Wout;
        bpix[c] = b * PHW + oy * STRIDE * PW + ox * STRIDE;
        bblk[c] = (blk ^ (col & 7)) * 8;
    }
    // ---- A source precompute ----
    const int arow = t >> 3;
    const int ablk = ((t & 7) ^ (arow & 7)) * 8;
    const int wbase = (t & 448) * 16;

    const int wid = t >> 6, l = t & 63;
    const int wm = wid >> 1, wn = wid & 1;
    const int l16 = l & 15, lhi = l >> 4;

    const f32x4 zero4 = {0.f, 0.f, 0.f, 0.f};
    f32x4 acc[4][4];
    #pragma unroll
    for (int i = 0; i < 4; ++i)
        #pragma unroll
        for (int j = 0; j < 4; ++j) acc[i][j] = zero4;

    for (int s = 0; s < steps_pb; ++s) {
        const int g     = g0 + s;
        const int phase = g >> sppsh;
        const int cs    = g - (phase << sppsh);
        const int pair  = phase / 9;                 // 0,1,2
        const int tap   = phase - pair * 9;
        const int pA = (0x100 >> (pair * 4)) & 15;   // h,h,m
        const int pB = (0x010 >> (pair * 4)) & 15;   // h,m,h
        const int ci0 = cs * 64;
        const int tapoff = (tap / 3) * PW + (tap % 3);

        const u16* Ag = wT + ((long)(pA * 9 + tap) * 1024 + m0) * Cin + ci0 + ablk;
        #pragma unroll
        for (int c = 0; c < 4; ++c)
            GLOAD_LDS16(Ag + (long)(c * 64 + arow) * Cin,
                        (char*)Alds + c * 8192 + wbase);
        const u16* Bg = xp + (long)pB * PSx + (long)tapoff * Cin + ci0;
        #pragma unroll
        for (int c = 0; c < 2; ++c)
            GLOAD_LDS16(Bg + (long)bpix[c] * Cin + bblk[c],
                        (char*)Blds + c * 8192 + wbase);

        __syncthreads();

        #pragma unroll
        for (int j = 0; j < 2; ++j) {
            const int kb = j * 64 + lhi * 16;
            half8 af[4], bf[4];
            #pragma unroll
            for (int f = 0; f < 4; ++f) {
                const int row = wm * 64 + f * 16 + l16;
                af[f] = *(const half8*)((const char*)Alds + row * 128
                                        + (kb ^ ((row & 7) << 4)));
            }
            #pragma unroll
            for (int f = 0; f < 4; ++f) {
                const int cc = wn * 64 + f * 16 + l16;
                bf[f] = *(const half8*)((const char*)Blds + cc * 128
                                        + (kb ^ ((cc & 7) << 4)));
            }
            #pragma unroll
            for (int fm = 0; fm < 4; ++fm)
                #pragma unroll
                for (int fn = 0; fn < 4; ++fn)
                    acc[fm][fn] = __builtin_amdgcn_mfma_f32_16x16x32_f16(
                        af[fm], bf[fn], acc[fm][fn], 0, 0, 0);
        }
        __syncthreads();
    }

    const long pbase = (long)bz * 1024;
    #pragma unroll
    for (int fm = 0; fm < 4; ++fm) {
        #pragma unroll
        for (int r = 0; r < 4; ++r) {
            const long mrow = pbase + m0 + wm * 64 + fm * 16 + lhi * 4 + r;
            float* prow = partial + mrow * Npad + n0 + wn * 64 + l16;
            #pragma unroll
            for (int fn = 0; fn < 4; ++fn)
                prow[fn * 16] = acc[fm][fn][r];
        }
    }
}

// ---------------------------------------------------------------------------
// Sum K-chunk partials, /4096 + bias + leakyReLU -> padded NHWC fp16 2-plane.
// ---------------------------------------------------------------------------
__global__ __launch_bounds__(256)
void reduce_nhwc(const float* __restrict__ partial, const float* __restrict__ bias,
                 u16* __restrict__ yp,
                 const int S, const int Npad, const int Ntot,
                 const int Wout, const int PW, const int PHW, const long PSy)
{
    __shared__ float lds[64][65];
    const int t  = threadIdx.x;
    const int m0 = blockIdx.x * 64;
    const int n0 = blockIdx.y * 64;
    const int HWout = Wout * Wout;

    const int lm = t >> 6, ln = t & 63;
    for (int r = 0; r < 16; ++r) {
        const int m = r * 4 + lm;
        const int n = n0 + ln;
        float v = 0.f;
        if (n < Ntot) {
            for (int s = 0; s < S; ++s)
                v += partial[((long)s * 1024 + m0 + m) * Npad + n];
            v = v * (1.0f / 4096.0f) + bias[m0 + m];
            v = (v >= 0.f) ? v : 0.1f * v;
        }
        lds[m][ln] = v;
    }
    __syncthreads();

    const int wn_ = t >> 6, wci = t & 63;
    for (int r = 0; r < 16; ++r) {
        const int pr = r * 4 + wn_;
        const int nn = n0 + pr;
        if (nn < Ntot) {
            const int b = nn / HWout;
            const int p = nn - b * HWout;
            const int py = p / Wout + 1, px = p % Wout + 1;
            const long off = ((long)b * PHW + py * PW + px) * 1024 + m0 + wci;
            const float vs = lds[wci][pr] * 16.0f;   // activation scale
            u16 h = f2h(vs);
            u16 m = f2h(vs - h2f(h));
            yp[off] = h; yp[PSy + off] = m;
        }
    }
}

// ---------------------------------------------------------------------------
// conv4 epilogue: partials -> fp32 NCHW (feeds fc1)
// ---------------------------------------------------------------------------
__global__ __launch_bounds__(256)
void reduce_f32(const float* __restrict__ partial, const float* __restrict__ bias,
                float* __restrict__ yf,
                const int S, const int Npad, const int Ntot, const int HWout)
{
    const long idx = (long)blockIdx.x * 256 + threadIdx.x;
    if (idx >= (long)1024 * Ntot) return;
    const int m = (int)(idx / Ntot);
    const int n = (int)(idx - (long)m * Ntot);
    float v = 0.f;
    for (int s = 0; s < S; ++s)
        v += partial[((long)s * 1024 + m) * Npad + n];
    v = v * (1.0f / 4096.0f) + bias[m];
    v = (v >= 0.f) ? v : 0.1f * v;
    const int b = n / HWout, pix = n - b * HWout;
    yf[((long)b * 1024 + m) * HWout + pix] = v;
}

// ---------------------------------------------------------------------------
// fc1: out(16,4096) = x(16,50176) @ W(50176,4096); 196 K-chunks of 256.
// grid (4,196) = 784 blocks -> ~3 blocks/CU, 12 waves/CU (was 392 -> 1.5/CU,
// thin for an 822MB streaming read). float4 weight loads kept.
// ---------------------------------------------------------------------------
__global__ __launch_bounds__(256)
void fc1_partial(const float* __restrict__ x, const float* __restrict__ w,
                 float* __restrict__ part)
{
    __shared__ float xs[256][16];   // 16KB
    const int tid = threadIdx.x;
    const int n   = blockIdx.x * 1024 + tid * 4;
    const int kc  = blockIdx.y;
    const int k0  = kc * 256;

    for (int i = tid; i < 256 * 16; i += 256) {
        const int j = i >> 4;
        const int b = i & 15;
        xs[j][b] = x[(size_t)b * 50176 + k0 + j];
    }
    __syncthreads();

    f32x4 acc[16];
    #pragma unroll
    for (int b = 0; b < 16; ++b) acc[b] = (f32x4){0.f, 0.f, 0.f, 0.f};

    for (int j = 0; j < 256; ++j) {
        const f32x4 wv = *(const f32x4*)&w[(size_t)(k0 + j) * 4096 + n];
        #pragma unroll
        for (int b = 0; b < 16; ++b) {
            const float xb = xs[j][b];
            #pragma unroll
            for (int c = 0; c < 4; ++c)
                acc[b][c] = fmaf(xb, wv[c], acc[b][c]);
        }
    }

    #pragma unroll
    for (int b = 0; b < 16; ++b)
        *(f32x4*)&part[((size_t)kc * 16 + b) * 4096 + n] = acc[b];
}

__global__ __launch_bounds__(256)
void fc1_reduce(const float* __restrict__ part, const float* __restrict__ bias,
                float* __restrict__ y)
{
    const int i = blockIdx.x * 256 + threadIdx.x;
    float s = 0.f;
    for (int kc = 0; kc < 196; ++kc) s += part[(size_t)kc * 65536 + i];
    s += bias[i & 4095];
    y[i] = (s >= 0.f) ? s : 0.1f * s;
}

// ---------------------------------------------------------------------------
// fc2: out(16,1470) = x(16,4096) @ W(4096,1470); K split into 32 chunks.
// ---------------------------------------------------------------------------
__global__ __launch_bounds__(256)
void fc2_partial(const float* __restrict__ x, const float* __restrict__ w,
                 float* __restrict__ part)
{
    __shared__ float xs[128][16];
    const int tid = threadIdx.x;
    const int n   = blockIdx.x * 256 + tid;
    const int kc  = blockIdx.y;
    const int k0  = kc * 128;

    for (int i = tid; i < 128 * 16; i += 256) {
        const int j = i >> 4;
        const int b = i & 15;
        xs[j][b] = x[(size_t)b * 4096 + k0 + j];
    }
    __syncthreads();

    float acc[16] = {};
    if (n < 1470) {
        for (int j = 0; j < 128; ++j) {
            const float wv = w[(size_t)(k0 + j) * 1470 + n];
            #pragma unroll
            for (int b4 = 0; b4 < 4; ++b4) {
                const float4 xv = *(const float4*)&xs[j][b4 * 4];
                acc[b4*4+0] = fmaf(xv.x, wv, acc[b4*4+0]);
                acc[b4*4+1] = fmaf(xv.y, wv, acc[b4*4+1]);
                acc[b4*4+2] = fmaf(xv.z, wv, acc[b4*4+2]);
                acc[b4*4+3] = fmaf(xv.w, wv, acc[b4*4+3]);
            }
        }
        #pragma unroll
        for (int b = 0; b < 16; ++b)
            part[((size_t)kc * 16 + b) * 1470 + n] = acc[b];
    }
}

__global__ __launch_bounds__(256)
void fc2_reduce(const float* __restrict__ part, const float* __restrict__ bias,
                float* __restrict__ y)
{
    const int i = blockIdx.x * 256 + threadIdx.x;
    if (i >= 16 * 1470) return;
    float s = 0.f;
    for (int kc = 0; kc < 32; ++kc) s += part[(size_t)kc * 23520 + i];
    const int n = i % 1470;
    s += bias[n];
    y[i] = 1.0f / (1.0f + expf(-s));
}

// ---------------------------------------------------------------------------
// Decode + per-batch NMS (mirrors JAX semantics incl. stable argsort)
// ---------------------------------------------------------------------------
__global__ __launch_bounds__(128)
void decode_nms(const float* __restrict__ out2, float* __restrict__ dout)
{
    const int b = blockIdx.x;
    const int t = threadIdx.x;
    const float cell = 1.0f / 7.0f;
    const float* o = out2 + (size_t)b * 1470;

    __shared__ float bx[98][4];
    __shared__ float sc[98];
    __shared__ float area[98];
    __shared__ int   order[98];
    __shared__ int   rankof[98];
    __shared__ int   supp[98];
    __shared__ int   keep_s[98];

    if (t < 98) {
        const int gA = t / 14;
        const int r  = t % 14;
        const int gB = r >> 1;
        const int nb = r & 1;
        const int base = gB * 210 + gA * 30 + nb * 5;
        const float v0 = o[base + 0];
        const float v1 = o[base + 1];
        const float w  = o[base + 2];
        const float h  = o[base + 3];
        const float s  = o[base + 4];
        const float cx = v0 * cell + (float)gA * cell;
        const float cy = v1 * cell + (float)gB * cell;
        const float x1 = cx - 0.5f * w;
        const float y1 = cy - 0.5f * h;
        const float x2 = cx + 0.5f * w;
        const float y2 = cy + 0.5f * h;
        bx[t][0] = x1; bx[t][1] = y1; bx[t][2] = x2; bx[t][3] = y2;
        sc[t] = s;
        area[t] = (x2 - x1) * (y2 - y1);
        supp[t] = 0;
        keep_s[t] = 0;
    }
    __syncthreads();

    if (t < 98) {
        const float si = (sc[t] >= CONF_THR) ? sc[t] : -1.0f;
        int rank = 0;
        for (int j = 0; j < 98; ++j) {
            const float sj = (sc[j] >= CONF_THR) ? sc[j] : -1.0f;
            rank += (sj > si) || (sj == si && j < t);
        }
        order[rank] = t;
        rankof[t] = rank;
    }
    __syncthreads();

    for (int i = 0; i < 98; ++i) {
        const int oi = order[i];
        const bool ki = (sc[oi] >= CONF_THR) && (supp[i] == 0);
        if (t == 0) keep_s[i] = ki ? 1 : 0;
        if (ki && t < 98 && t > i) {
            const int oj = order[t];
            const float xx1 = fmaxf(bx[oi][0], bx[oj][0]);
            const float yy1 = fmaxf(bx[oi][1], bx[oj][1]);
            const float xx2 = fminf(bx[oi][2], bx[oj][2]);
            const float yy2 = fminf(bx[oi][3], bx[oj][3]);
            const float iw = fmaxf(xx2 - xx1, 0.f);
            const float ih = fmaxf(yy2 - yy1, 0.f);
            const float inter = iw * ih;
            const float iou = inter / (area[oi] + area[oj] - inter);
            if (iou > IOU_THR) supp[t] = 1;
        }
        __syncthreads();
    }

    float* out_boxes  = dout;
    float* out_scores = dout + 6272;
    float* out_keep   = dout + 7840;
    float* out_labels = dout + 9408;

    if (t < 98) {
        const bool kp = keep_s[rankof[t]] != 0;
        const size_t bi = ((size_t)b * 98 + t) * 4;
        out_boxes[bi + 0] = kp ? bx[t][0] * IMG_SZ : 0.f;
        out_boxes[bi + 1] = kp ? bx[t][1] * IMG_SZ : 0.f;
        out_boxes[bi + 2] = kp ? bx[t][2] * IMG_SZ : 0.f;
        out_boxes[bi + 3] = kp ? bx[t][3] * IMG_SZ : 0.f;
        out_scores[(size_t)b * 98 + t] = kp ? sc[t] : 0.f;
        out_keep[(size_t)b * 98 + t]   = kp ? 1.f : 0.f;
    }
    for (int i = t; i < 49 * 20; i += 128) {
        const int g  = i / 20;
        const int c  = i - g * 20;
        const int gA = g / 7;
        const int gB = g - gA * 7;
        out_labels[(size_t)b * 980 + i] = o[gB * 210 + gA * 30 + 10 + c];
    }
}

// ---------------------------------------------------------------------------
extern "C" void kernel_launch(void* const* d_in, const int* in_sizes, int n_in,
                              void* d_out, int out_size, void* d_ws, size_t ws_size,
                              hipStream_t stream)
{
    (void)in_sizes; (void)n_in; (void)out_size; (void)ws_size;

    const float* features = (const float*)d_in[0];
    const float* w1 = (const float*)d_in[1];
    const float* b1 = (const float*)d_in[2];
    const float* w2 = (const float*)d_in[3];
    const float* b2 = (const float*)d_in[4];
    const float* w3 = (const float*)d_in[5];
    const float* b3 = (const float*)d_in[6];
    const float* w4 = (const float*)d_in[7];
    const float* b4 = (const float*)d_in[8];
    const float* fc1_w = (const float*)d_in[9];
    const float* fc1_b = (const float*)d_in[10];
    const float* fc2_w = (const float*)d_in[11];
    const float* fc2_b = (const float*)d_in[12];

    // ---- workspace plan (~191 MB, r10 layout) ----
    char* W = (char*)d_ws;
    size_t o = 0;
    auto alloc = [&](size_t bytes) -> char* {
        char* r = W + o; o += (bytes + 255) & ~(size_t)255; return r;
    };
    u16*   wT      = (u16*)  alloc(75497472ULL);  // 2*9*1024*2048*2 (per-layer reuse)
    u16*   xp      = (u16*)  alloc(33554432ULL);  // features: 2*16*256*2048*2
    u16*   actA    = (u16*)  alloc(16777216ULL);  // conv1 out: 2*16*256*1024*2
    float* a4      = (float*)alloc(3211264ULL);   // conv4 out fp32 NCHW
    float* partial = (float*)alloc(58720256ULL);  // max(4*1024*3200, 16*1024*896)*4
    float* fc1o    = (float*)alloc(262144ULL);
    float* part2   = (float*)alloc(3010560ULL);
    float* fc2o    = (float*)alloc(94080ULL);
    (void)alloc(4096);
    // aliases (lifetimes verified):
    float* part1 = partial;                       // 51.4MB (=196*65536*4) <= 56MB;
                                                  // partial dead after reduce_f32
    u16*   actB  = (u16*)(xp + (24u << 20) / 2);  // 5.3MB @ xp+24MB, conv2..conv4
                                                  // (xp dead after conv1)

    const long PSxp = 8388608L;   // 16*256*2048
    const long PSa  = 4194304L;   // 16*256*1024
    const long PSb  = 1327104L;   // 16*81*1024

    // features -> padded NHWC 2-plane (x16)
    pad_split<<<512, 256, 0, stream>>>(features, xp, 2048, 14, 14, 16, 256, PSxp);

    // conv1: Cin=2048; 27 phases * 32 cs = 864 steps, z=4 -> 216/block (grid 400 = 8*50)
    wsplit_kernel<<<dim3(8, 1024), 256, 0, stream>>>(w1, wT, 2048);
    hipMemsetAsync(actA, 0, 16777216ULL, stream);
    conv_mfma<1><<<dim3(4, 25, 4), 512, 0, stream>>>(
        xp, wT, partial, 2048, 16, 256, 14, 3136, 5, 216, 3200, PSxp);
    hipMemsetAsync(actB, 0, 5308416ULL, stream);       // xp dead; zero pads
    reduce_nhwc<<<dim3(16, 49), 256, 0, stream>>>(partial, b1, actA,
                                                  4, 3200, 3136, 14, 16, 256, PSa);

    // conv2: Cin=1024, stride 2; 27 phases * 16 cs, z=16 -> 27/block (grid 448 = 8*56)
    wsplit_kernel<<<dim3(4, 1024), 256, 0, stream>>>(w2, wT, 1024);
    conv_mfma<2><<<dim3(4, 7, 16), 512, 0, stream>>>(
        actA, wT, partial, 1024, 16, 256, 7, 784, 4, 27, 896, PSa);
    reduce_nhwc<<<dim3(16, 13), 256, 0, stream>>>(partial, b2, actB,
                                                  16, 896, 784, 7, 9, 81, PSb);

    // conv3: 7x7, padded 9x9
    wsplit_kernel<<<dim3(4, 1024), 256, 0, stream>>>(w3, wT, 1024);
    conv_mfma<1><<<dim3(4, 7, 16), 512, 0, stream>>>(
        actB, wT, partial, 1024, 9, 81, 7, 784, 4, 27, 896, PSb);
    reduce_nhwc<<<dim3(16, 13), 256, 0, stream>>>(partial, b3, actB,
                                                  16, 896, 784, 7, 9, 81, PSb);

    // conv4 -> fp32 NCHW a4
    wsplit_kernel<<<dim3(4, 1024), 256, 0, stream>>>(w4, wT, 1024);
    conv_mfma<1><<<dim3(4, 7, 16), 512, 0, stream>>>(
        actB, wT, partial, 1024, 9, 81, 7, 784, 4, 27, 896, PSb);
    reduce_f32<<<3136, 256, 0, stream>>>(partial, b4, a4, 16, 896, 784, 49);

    // fc1 (float4 loads, 196-way K-split, 784 blocks; part1 aliases partial)
    fc1_partial<<<dim3(4, 196), 256, 0, stream>>>(a4, fc1_w, part1);
    fc1_reduce<<<256, 256, 0, stream>>>(part1, fc1_b, fc1o);

    fc2_partial<<<dim3(6, 32), 256, 0, stream>>>(fc1o, fc2_w, part2);
    fc2_reduce<<<92, 256, 0, stream>>>(part2, fc2_b, fc2o);

    decode_nms<<<16, 128, 0, stream>>>(fc2o, (float*)d_out);
}